// Round 7
// baseline (394.216 us; speedup 1.0000x reference)
//
#include <hip/hip_runtime.h>
#include <stdint.h>

// ---------------------------------------------------------------------------
// GQA forward: y = OutProj( Attention( QKVProj(x) ) )
// B=2, S=2048, EMB=2048, NQH=16, HD=128, NKV=4, G=4. Non-causal softmax.
// R14: MEASUREMENT ROUND. Kernels identical to R13 (best: 278.9 us).
//   cvt_all, gemm256<0>, gemm256x128 are each launched TWICE (idempotent:
//   deterministic pure functions of stable inputs, same-stream serialized,
//   identical bytes written twice -> passed/absmax unchanged).
//   dur_us - 278.9 = cvt + gemm0 + gemm1 exactly; resolves the attribution
//   contradiction (top-5 bounds both gemms < 76 us, yet modeled kernel sum
//   leaves ~110 us unattributed). Next round reverts the duplicates and
//   targets whichever world the number indicates.
// ---------------------------------------------------------------------------

typedef short s8v __attribute__((ext_vector_type(8)));   // 8 bf16 = 16 B
typedef float f4  __attribute__((ext_vector_type(4)));
typedef unsigned short u16;

#define GLD_LDS(g, l) __builtin_amdgcn_global_load_lds(                     \
    (const __attribute__((address_space(1))) void*)(g),                     \
    (__attribute__((address_space(3))) void*)(l), 16, 0, 0)

__device__ __forceinline__ u16 f2bf(float f) {
    union { float f; uint32_t u; } v; v.f = f;
    uint32_t u = v.u;
    return (u16)((u + 0x7fffu + ((u >> 16) & 1u)) >> 16);   // RNE
}

__device__ __forceinline__ float fexp2(float x) {
#if __has_builtin(__builtin_amdgcn_exp2f)
    return __builtin_amdgcn_exp2f(x);
#else
    return exp2f(x);
#endif
}

// ----------------------- fused fp32 -> bf16 cast ----------------------------
__global__ void cvt_all(const float* __restrict__ x,  const float* __restrict__ wq,
                        const float* __restrict__ wk, const float* __restrict__ wv,
                        const float* __restrict__ wo_,
                        u16* __restrict__ xb, u16* __restrict__ wqkv,
                        u16* __restrict__ wob)
{
    int i = blockIdx.x * blockDim.x + threadIdx.x;
    const float4* s; ushort4* d; int so, dofs;
    if (i < 2097152)      { s = (const float4*)x;   d = (ushort4*)xb;   so = i;           dofs = so; }
    else if (i < 3145728) { s = (const float4*)wq;  d = (ushort4*)wqkv; so = i - 2097152; dofs = so; }
    else if (i < 3407872) { s = (const float4*)wk;  d = (ushort4*)wqkv; so = i - 3145728; dofs = so + 1048576; }
    else if (i < 3670016) { s = (const float4*)wv;  d = (ushort4*)wqkv; so = i - 3407872; dofs = so + 1310720; }
    else                  { s = (const float4*)wo_; d = (ushort4*)wob;  so = i - 3670016; dofs = so; }
    float4 v = s[so];
    ushort4 o;
    o.x = f2bf(v.x); o.y = f2bf(v.y); o.z = f2bf(v.z); o.w = f2bf(v.w);
    d[dofs] = o;
}

// ------------------- GEMM: C = A * B^T  (256x256, 8-phase) ------------------
// MODE 0: QKV epilogue -> qkOut [M,2560]; V -> vtOut transposed.
template<int MODE>
__global__ __launch_bounds__(512, 1)
void gemm256(const u16* __restrict__ A, const u16* __restrict__ Bm,
             int M, int N, int K,
             u16* __restrict__ qkOut, u16* __restrict__ vtOut,
             float* __restrict__ fOut)
{
    __shared__ __attribute__((aligned(16))) u16 lds[2][2][2][8192];

    const int tid  = threadIdx.x;
    const int lane = tid & 63, quad = lane >> 4, l16 = lane & 15;
    const int wave = tid >> 6;
    const int wr = wave >> 2, wc = wave & 3;   // wave grid 2 x 4

    int bx, by;
    {
        const int nwgx = gridDim.x;
        const int nwg  = nwgx * gridDim.y;
        const int flat = blockIdx.y * nwgx + blockIdx.x;
        const int nflat = (flat & 7) * (nwg >> 3) + (flat >> 3);
        bx = nflat % nwgx; by = nflat / nwgx;
    }
    const int m0 = by * 256, n0 = bx * 256;
    const int NT = K >> 6;

    f4 acc[8][4] = {};

#define VMC6() asm volatile("s_waitcnt vmcnt(6)" ::: "memory")
#define VMC0() asm volatile("s_waitcnt vmcnt(0)" ::: "memory")
#define BAR()  __builtin_amdgcn_s_barrier()

#define STG(bf, op, h, t) if ((t) < NT) {                                   \
        const u16* gb = (op) ? Bm : A;                                      \
        const int rb = ((op) ? n0 : m0) + (h) * 128;                        \
        _Pragma("unroll")                                                   \
        for (int j = 0; j < 2; j++) {                                       \
            int s_ = j * 512 + tid;                                         \
            int r_ = s_ >> 3, cc = s_ & 7;                                  \
            GLD_LDS(gb + (size_t)(rb + r_) * K + (t) * 64                   \
                       + ((cc ^ (r_ & 7)) << 3),                            \
                    &lds[bf][op][h][(j * 512 + (tid & ~63)) * 8]);          \
        } }

#define RD_A(bf, qm, ar) {                                                  \
        _Pragma("unroll")                                                   \
        for (int f = 0; f < 4; f++) {                                       \
            int r_ = (qm) * 64 + f * 16 + l16;                              \
            _Pragma("unroll")                                               \
            for (int kc = 0; kc < 2; kc++)                                  \
                ar[f][kc] = *(const s8v*)(&lds[bf][0][wr]                   \
                    [r_ * 64 + (((kc * 4 + quad) ^ (r_ & 7)) << 3)]);       \
        } }

#define RD_B(bf, qn, br) {                                                  \
        _Pragma("unroll")                                                   \
        for (int f = 0; f < 2; f++) {                                       \
            int r_ = (wc & 1) * 64 + ((qn) * 2 + f) * 16 + l16;             \
            _Pragma("unroll")                                               \
            for (int kc = 0; kc < 2; kc++)                                  \
                br[f][kc] = *(const s8v*)(&lds[bf][1][wc >> 1]              \
                    [r_ * 64 + (((kc * 4 + quad) ^ (r_ & 7)) << 3)]);       \
        } }

#define MM(qm, qn, ar, br) {                                                \
        __builtin_amdgcn_s_setprio(1);                                      \
        _Pragma("unroll")                                                   \
        for (int f = 0; f < 4; f++)                                         \
            _Pragma("unroll")                                               \
            for (int g = 0; g < 2; g++) {                                   \
                acc[(qm)*4+f][(qn)*2+g] = __builtin_amdgcn_mfma_f32_16x16x32_bf16( \
                    ar[f][0], br[g][0], acc[(qm)*4+f][(qn)*2+g], 0, 0, 0);  \
                acc[(qm)*4+f][(qn)*2+g] = __builtin_amdgcn_mfma_f32_16x16x32_bf16( \
                    ar[f][1], br[g][1], acc[(qm)*4+f][(qn)*2+g], 0, 0, 0);  \
            }                                                               \
        __builtin_amdgcn_s_setprio(0); }

    STG(0,1,0,0); STG(0,1,1,0); STG(0,0,0,0); STG(0,0,1,0);
    STG(1,1,0,1); STG(1,1,1,1); STG(1,0,0,1);
    VMC6(); BAR();

    for (int T = 0; T < NT; T += 2) {
        const bool more = (T + 2 < NT);
        s8v a0[4][2], a1[4][2], b0[2][2], b1[2][2];
        RD_A(0,0,a0); RD_B(0,0,b0);
        STG(1,0,1,T+1);
        BAR(); MM(0,0,a0,b0); BAR();
        RD_B(0,1,b1);
        BAR(); MM(0,1,a0,b1); BAR();
        RD_A(0,1,a1);
        STG(0,1,0,T+2);
        BAR(); MM(1,0,a1,b0); BAR();
        STG(0,1,1,T+2); STG(0,0,0,T+2);
        BAR(); MM(1,1,a1,b1);
        if (more) { VMC6(); } else { VMC0(); }
        BAR();
        RD_A(1,0,a0); RD_B(1,0,b0);
        STG(0,0,1,T+2);
        BAR(); MM(0,0,a0,b0); BAR();
        RD_B(1,1,b1);
        BAR(); MM(0,1,a0,b1); BAR();
        RD_A(1,1,a1);
        STG(1,1,0,T+3);
        BAR(); MM(1,0,a1,b0); BAR();
        STG(1,1,1,T+3); STG(1,0,0,T+3);
        BAR(); MM(1,1,a1,b1);
        if (more) { VMC6(); } else { VMC0(); }
        BAR();
    }
#undef STG
#undef RD_A
#undef RD_B
#undef MM

    if (MODE == 0) {
        if (n0 < 2560) {
            const float qs = (n0 < 2048)
                ? (0.08838834764831845f * 1.4426950408889634f) : 1.0f;
            #pragma unroll
            for (int mi = 0; mi < 8; mi++) {
                int gm0 = m0 + wr * 128 + mi * 16 + quad * 4;
                #pragma unroll
                for (int ni = 0; ni < 4; ni++) {
                    int gn = n0 + wc * 64 + ni * 16 + l16;
                    #pragma unroll
                    for (int r = 0; r < 4; r++)
                        qkOut[(size_t)(gm0 + r) * 2560 + gn] = f2bf(acc[mi][ni][r] * qs);
                }
            }
        } else {
            #pragma unroll
            for (int mi = 0; mi < 8; mi++) {
                int gm0 = m0 + wr * 128 + mi * 16 + quad * 4;
                int bb = gm0 >> 11, s = gm0 & 2047;
                #pragma unroll
                for (int ni = 0; ni < 4; ni++) {
                    int gn = n0 + wc * 64 + ni * 16 + l16;
                    int dd = gn - 2560;
                    ushort4 pk;
                    pk.x = f2bf(acc[mi][ni][0]); pk.y = f2bf(acc[mi][ni][1]);
                    pk.z = f2bf(acc[mi][ni][2]); pk.w = f2bf(acc[mi][ni][3]);
                    *(ushort4*)(vtOut +
                        ((size_t)(bb * 4 + (dd >> 7)) * 128 + (dd & 127)) * 2048 + s) = pk;
                }
            }
        }
    } else {
        #pragma unroll
        for (int mi = 0; mi < 8; mi++) {
            int gm0 = m0 + wr * 128 + mi * 16 + quad * 4;
            #pragma unroll
            for (int ni = 0; ni < 4; ni++) {
                int gn = n0 + wc * 64 + ni * 16 + l16;
                #pragma unroll
                for (int r = 0; r < 4; r++)
                    fOut[(size_t)(gm0 + r) * N + gn] = acc[mi][ni][r];
            }
        }
    }
#undef VMC6
#undef VMC0
#undef BAR
}

// ---------------- GEMM: C = A * B^T  (256x128, 4-phase, fp32 out) -----------
__global__ __launch_bounds__(512, 1)
void gemm256x128(const u16* __restrict__ A, const u16* __restrict__ Bm,
                 int M, int N, int K, float* __restrict__ fOut)
{
    __shared__ __attribute__((aligned(16))) u16 lds[2][3][8192];

    const int tid  = threadIdx.x;
    const int lane = tid & 63, quad = lane >> 4, l16 = lane & 15;
    const int wave = tid >> 6;
    const int wr = wave >> 2, wc = wave & 3;

    int bx, by;
    {
        const int nwgx = gridDim.x;
        const int nwg  = nwgx * gridDim.y;
        const int flat = blockIdx.y * nwgx + blockIdx.x;
        const int nflat = (flat & 7) * (nwg >> 3) + (flat >> 3);
        bx = nflat % nwgx; by = nflat / nwgx;
    }
    const int m0 = by * 256, n0 = bx * 128;
    const int NT = K >> 6;

    f4 acc[8][2] = {};

#define VMC2() asm volatile("s_waitcnt vmcnt(2)" ::: "memory")
#define VMC0() asm volatile("s_waitcnt vmcnt(0)" ::: "memory")
#define BAR()  __builtin_amdgcn_s_barrier()

#define STG(bf, u, t) if ((t) < NT) {                                       \
        const u16* gb = ((u) == 2) ? Bm : A;                                \
        const int rb = ((u) == 2) ? n0 : (m0 + (u) * 128);                  \
        _Pragma("unroll")                                                   \
        for (int j = 0; j < 2; j++) {                                       \
            int s_ = j * 512 + tid;                                         \
            int r_ = s_ >> 3, cc = s_ & 7;                                  \
            GLD_LDS(gb + (size_t)(rb + r_) * K + (t) * 64                   \
                       + ((cc ^ (r_ & 7)) << 3),                            \
                    &lds[bf][u][(j * 512 + (tid & ~63)) * 8]);              \
        } }

#define RD_A(bf, qm, ar) {                                                  \
        _Pragma("unroll")                                                   \
        for (int f = 0; f < 4; f++) {                                       \
            int r_ = (qm) * 64 + f * 16 + l16;                              \
            _Pragma("unroll")                                               \
            for (int kc = 0; kc < 2; kc++)                                  \
                ar[f][kc] = *(const s8v*)(&lds[bf][wr]                      \
                    [r_ * 64 + (((kc * 4 + quad) ^ (r_ & 7)) << 3)]);       \
        } }

#define RD_B(bf, br) {                                                      \
        _Pragma("unroll")                                                   \
        for (int f = 0; f < 2; f++) {                                       \
            int r_ = wc * 32 + f * 16 + l16;                                \
            _Pragma("unroll")                                               \
            for (int kc = 0; kc < 2; kc++)                                  \
                br[f][kc] = *(const s8v*)(&lds[bf][2]                       \
                    [r_ * 64 + (((kc * 4 + quad) ^ (r_ & 7)) << 3)]);       \
        } }

#define MM(qm, ar, br) {                                                    \
        __builtin_amdgcn_s_setprio(1);                                      \
        _Pragma("unroll")                                                   \
        for (int f = 0; f < 4; f++)                                         \
            _Pragma("unroll")                                               \
            for (int g = 0; g < 2; g++) {                                   \
                acc[(qm)*4+f][g] = __builtin_amdgcn_mfma_f32_16x16x32_bf16( \
                    ar[f][0], br[g][0], acc[(qm)*4+f][g], 0, 0, 0);         \
                acc[(qm)*4+f][g] = __builtin_amdgcn_mfma_f32_16x16x32_bf16( \
                    ar[f][1], br[g][1], acc[(qm)*4+f][g], 0, 0, 0);         \
            }                                                               \
        __builtin_amdgcn_s_setprio(0); }

    STG(0,0,0); STG(0,1,0); STG(0,2,0);
    STG(1,2,1);
    VMC2(); BAR();

    for (int T = 0; T < NT; T += 2) {
        const bool more = (T + 2 < NT);
        s8v a0[4][2], a1[4][2], b[2][2];
        RD_A(0,0,a0); RD_B(0,b);
        STG(1,0,T+1); STG(1,1,T+1);
        BAR(); MM(0,a0,b); BAR();
        RD_A(0,1,a1);
        STG(0,2,T+2);
        BAR(); MM(1,a1,b);
        if (more) { VMC2(); } else { VMC0(); }
        BAR();
        RD_A(1,0,a0); RD_B(1,b);
        STG(0,0,T+2); STG(0,1,T+2);
        BAR(); MM(0,a0,b); BAR();
        RD_A(1,1,a1);
        STG(1,2,T+3);
        BAR(); MM(1,a1,b);
        if (more) { VMC2(); } else { VMC0(); }
        BAR();
    }
#undef STG
#undef RD_A
#undef RD_B
#undef MM
#undef VMC2
#undef VMC0
#undef BAR

    #pragma unroll
    for (int mi = 0; mi < 8; mi++) {
        int gm0 = m0 + wr * 128 + mi * 16 + quad * 4;
        #pragma unroll
        for (int ni = 0; ni < 2; ni++) {
            int gn = n0 + wc * 32 + ni * 16 + l16;
            #pragma unroll
            for (int r = 0; r < 4; r++)
                fOut[(size_t)(gm0 + r) * N + gn] = acc[mi][ni][r];
        }
    }
}

// ------------------------------- attention ----------------------------------
// grid = (B*NKV, S/64), 512 threads = 8 waves, wave = (head hh, m-half mh).
// Swapped QK^T, P staged via 8x ds_write_b64 + b128 reads; no max-tracking.
__global__ __launch_bounds__(512, 2)
void attn_kernel(const u16* __restrict__ qk, const u16* __restrict__ vt,
                 u16* __restrict__ ao)
{
    __shared__ __attribute__((aligned(16))) u16 Kb[2][64 * 128];  // 32 KB
    __shared__ __attribute__((aligned(16))) u16 Vb[2][128 * 64];  // 32 KB
    __shared__ __attribute__((aligned(16))) u16 Ps[8][32 * 72];   // 36 KB

    const int tid  = threadIdx.x;
    const int wave = tid >> 6, lane = tid & 63;
    const int quad = lane >> 4, l16 = lane & 15;
    const int bh = blockIdx.x;                 // 0..7 = b*4+h  (XCD = bh)
    const int b = bh >> 2, h = bh & 3;
    const int hh = wave >> 1, mh = wave & 1;   // head-in-group, m-half
    const int hq = h * 4 + hh;                 // global q-head
    const int qs0 = blockIdx.y * 64;

    s8v aq[2][4];
    #pragma unroll
    for (int mt = 0; mt < 2; mt++) {
        const u16* qrow = qk + (size_t)(b * 2048 + qs0 + (mh * 2 + mt) * 16 + l16) * 2560
                             + hq * 128 + quad * 8;
        #pragma unroll
        for (int c4 = 0; c4 < 4; c4++) aq[mt][c4] = *(const s8v*)(qrow + c4 * 32);
    }

    s8v ones;
    #pragma unroll
    for (int j = 0; j < 8; j++) ones[j] = (short)0x3F80;   // bf16 1.0

    f4 o[2][9] = {};          // 8 d-channels + [8] = row-sum l_i

    const u16* kbase = qk + (size_t)(b * 2048) * 2560 + 2048 + h * 128;
    const u16* vbase = vt + (size_t)bh * 128 * 2048;
    u16* Pw = &Ps[wave][0];

    int bkb[4], bvb[2];
    #pragma unroll
    for (int c4 = 0; c4 < 4; c4++)
        bkb[c4] = l16 * 128 + (((c4 * 4 + quad) ^ (l16 & 7)) * 8);
    #pragma unroll
    for (int kc = 0; kc < 2; kc++)
        bvb[kc] = l16 * 64 + (((kc * 4 + quad) ^ (l16 & 7)) * 8);
    const int apb = l16 * 72 + quad * 8;        // + mt*1152 + kc*32
    const int psw = l16 * 72 + quad * 4;        // + mt*1152 + cg*16 (b64 write)

#define STAGE(CUR, S) {                                                       \
        _Pragma("unroll")                                                     \
        for (int i = 0; i < 2; i++) {                                         \
            const int c = wave + i * 8;                                       \
            int kr = c * 4 + (lane >> 4);                                     \
            int ksw = (lane & 15) ^ (kr & 7);                                 \
            GLD_LDS(kbase + (size_t)((S) + kr) * 2560 + ksw * 8,              \
                    &Kb[CUR][c * 512]);                                       \
            int vd = c * 8 + (lane >> 3);                                     \
            int vsw = (lane & 7) ^ (vd & 7);                                  \
            GLD_LDS(vbase + (size_t)vd * 2048 + (S) + vsw * 8,                \
                    &Vb[CUR][c * 512]);                                       \
        } }

#define STEP(CUR, S) {                                                        \
        __syncthreads();  /* completes buf CUR staging (issued last iter) */  \
        if ((S) + 64 < 2048) STAGE((CUR) ^ 1, (S) + 64);                      \
        s8v bk[4][4];                                                         \
        _Pragma("unroll")                                                     \
        for (int c4 = 0; c4 < 4; c4++)                                        \
            _Pragma("unroll")                                                 \
            for (int cg = 0; cg < 4; cg++)                                    \
                bk[c4][cg] = *(const s8v*)(&Kb[CUR][bkb[c4] + cg * 2048]);    \
        _Pragma("unroll")                                                     \
        for (int mt = 0; mt < 2; mt++) {                                      \
            f4 sc[4] = {};                                                    \
            _Pragma("unroll")                                                 \
            for (int c4 = 0; c4 < 4; c4++)                                    \
                _Pragma("unroll")                                             \
                for (int cg = 0; cg < 4; cg++)                                \
                    sc[cg] = __builtin_amdgcn_mfma_f32_16x16x32_bf16(         \
                        bk[c4][cg], aq[mt][c4], sc[cg], 0, 0, 0);             \
            _Pragma("unroll")                                                 \
            for (int cg = 0; cg < 4; cg++) {                                  \
                ushort4 pk;                                                   \
                pk.x = (u16)(__float_as_uint(fexp2(sc[cg][0])) >> 16);        \
                pk.y = (u16)(__float_as_uint(fexp2(sc[cg][1])) >> 16);        \
                pk.z = (u16)(__float_as_uint(fexp2(sc[cg][2])) >> 16);        \
                pk.w = (u16)(__float_as_uint(fexp2(sc[cg][3])) >> 16);        \
                *(ushort4*)(Pw + psw + mt * 1152 + cg * 16) = pk;             \
            }                                                                 \
        }                                                                     \
        s8v ap[2][2];                                                         \
        _Pragma("unroll")                                                     \
        for (int mt = 0; mt < 2; mt++)                                        \
            _Pragma("unroll")                                                 \
            for (int kc = 0; kc < 2; kc++)                                    \
                ap[mt][kc] = *(const s8v*)(Pw + apb + mt * 1152 + kc * 32);   \
        _Pragma("unroll")                                                     \
        for (int ch = 0; ch < 8; ch++) {                                      \
            s8v bv0 = *(const s8v*)(&Vb[CUR][bvb[0] + ch * 1024]);            \
            s8v bv1 = *(const s8v*)(&Vb[CUR][bvb[1] + ch * 1024]);            \
            _Pragma("unroll")                                                 \
            for (int mt = 0; mt < 2; mt++) {                                  \
                o[mt][ch] = __builtin_amdgcn_mfma_f32_16x16x32_bf16(          \
                    ap[mt][0], bv0, o[mt][ch], 0, 0, 0);                      \
                o[mt][ch] = __builtin_amdgcn_mfma_f32_16x16x32_bf16(          \
                    ap[mt][1], bv1, o[mt][ch], 0, 0, 0);                      \
            }                                                                 \
        }                                                                     \
        _Pragma("unroll")                                                     \
        for (int mt = 0; mt < 2; mt++) {                                      \
            o[mt][8] = __builtin_amdgcn_mfma_f32_16x16x32_bf16(               \
                ap[mt][0], ones, o[mt][8], 0, 0, 0);                          \
            o[mt][8] = __builtin_amdgcn_mfma_f32_16x16x32_bf16(               \
                ap[mt][1], ones, o[mt][8], 0, 0, 0);                          \
        } }

    STAGE(0, 0);
    for (int s0 = 0; s0 < 2048; s0 += 128) {
        STEP(0, s0);
        STEP(1, s0 + 64);
    }
#undef STEP
#undef STAGE

    #pragma unroll
    for (int mt = 0; mt < 2; mt++)
        #pragma unroll
        for (int r = 0; r < 4; r++) {
            float inv = 1.f / o[mt][8][r];
            int gm = b * 2048 + qs0 + (mh * 2 + mt) * 16 + quad * 4 + r;
            #pragma unroll
            for (int ch = 0; ch < 8; ch++)
                ao[(size_t)gm * 2048 + hq * 128 + ch * 16 + l16] =
                    f2bf(o[mt][ch][r] * inv);
        }
}

// ------------------------------- launcher -----------------------------------
extern "C" void kernel_launch(void* const* d_in, const int* in_sizes, int n_in,
                              void* d_out, int out_size, void* d_ws, size_t ws_size,
                              hipStream_t stream)
{
    const float* x  = (const float*)d_in[0];
    const float* Wq = (const float*)d_in[3];
    const float* Wk = (const float*)d_in[4];
    const float* Wv = (const float*)d_in[5];
    const float* Wo = (const float*)d_in[6];

    char* ws = (char*)d_ws;
    u16* xb   = (u16*)(ws);                 // 4096x2048
    u16* wqkv = (u16*)(ws + 16777216);      // 3072x2048
    u16* wo   = (u16*)(ws + 29360128);      // 2048x2048
    u16* qkb  = (u16*)(ws + 37748736);      // 4096x2560
    u16* vtb  = (u16*)(ws + 58720256);      // 2x4x128x2048
    u16* ao   = (u16*)(ws + 62914560);      // 4096x2048
    if (ws_size < 79691776u) return;

    // R14 measurement: each non-attn kernel launched twice (idempotent).
    // dur_us - 278.9 = cvt + gemm0 + gemm1 exactly.
    cvt_all<<<18432, 256, 0, stream>>>(x, Wq, Wk, Wv, Wo, xb, wqkv, wo);
    cvt_all<<<18432, 256, 0, stream>>>(x, Wq, Wk, Wv, Wo, xb, wqkv, wo);

    gemm256<0><<<dim3(12, 16), 512, 0, stream>>>(xb, wqkv, 4096, 3072, 2048,
                                                 qkb, vtb, nullptr);
    gemm256<0><<<dim3(12, 16), 512, 0, stream>>>(xb, wqkv, 4096, 3072, 2048,
                                                 qkb, vtb, nullptr);

    attn_kernel<<<dim3(8, 32), 512, 0, stream>>>(qkb, vtb, ao);

    gemm256x128<<<dim3(16, 16), 512, 0, stream>>>(ao, wo, 4096, 2048, 2048,
                                                  (float*)d_out);
    gemm256x128<<<dim3(16, 16), 512, 0, stream>>>(ao, wo, 4096, 2048, 2048,
                                                  (float*)d_out);
}

// Round 8
// 268.013 us; speedup vs baseline: 1.4709x; 1.4709x over previous
//
#include <hip/hip_runtime.h>
#include <stdint.h>

// ---------------------------------------------------------------------------
// GQA forward: y = OutProj( Attention( QKVProj(x) ) )
// B=2, S=2048, EMB=2048, NQH=16, HD=128, NKV=4, G=4. Non-causal softmax.
// R15 (post-measurement): R14 established cvt+g0+g1 ~= 106 us, launch gap
//   ~3 us, and a ~85 us fixed harness floor. gemm0 (~55 us @ 75% fill) is the
//   largest addressable kernel after attn.
//  - gemm0 rewritten as 256x192-tile 4-phase kernel: grid (16,16) = 256
//    blocks = 100% machine fill (N=3072=16*192). LDS 112 KB {A0,A1,B=24K}x2,
//    counted vmcnt(3) (B-unit = 3 loads). Choreography mirrors the verified
//    gemm256x128. Epilogue handles 2048/2560 boundaries per 16-wide fragment
//    (fragments never straddle: boundaries are multiples of 16).
//  - attn (R13, 76 us), gemm256x128 (out-proj), cvt unchanged; duplicates
//    removed.
// ---------------------------------------------------------------------------

typedef short s8v __attribute__((ext_vector_type(8)));   // 8 bf16 = 16 B
typedef float f4  __attribute__((ext_vector_type(4)));
typedef unsigned short u16;

#define GLD_LDS(g, l) __builtin_amdgcn_global_load_lds(                     \
    (const __attribute__((address_space(1))) void*)(g),                     \
    (__attribute__((address_space(3))) void*)(l), 16, 0, 0)

__device__ __forceinline__ u16 f2bf(float f) {
    union { float f; uint32_t u; } v; v.f = f;
    uint32_t u = v.u;
    return (u16)((u + 0x7fffu + ((u >> 16) & 1u)) >> 16);   // RNE
}

__device__ __forceinline__ float fexp2(float x) {
#if __has_builtin(__builtin_amdgcn_exp2f)
    return __builtin_amdgcn_exp2f(x);
#else
    return exp2f(x);
#endif
}

// ----------------------- fused fp32 -> bf16 cast ----------------------------
__global__ void cvt_all(const float* __restrict__ x,  const float* __restrict__ wq,
                        const float* __restrict__ wk, const float* __restrict__ wv,
                        const float* __restrict__ wo_,
                        u16* __restrict__ xb, u16* __restrict__ wqkv,
                        u16* __restrict__ wob)
{
    int i = blockIdx.x * blockDim.x + threadIdx.x;
    const float4* s; ushort4* d; int so, dofs;
    if (i < 2097152)      { s = (const float4*)x;   d = (ushort4*)xb;   so = i;           dofs = so; }
    else if (i < 3145728) { s = (const float4*)wq;  d = (ushort4*)wqkv; so = i - 2097152; dofs = so; }
    else if (i < 3407872) { s = (const float4*)wk;  d = (ushort4*)wqkv; so = i - 3145728; dofs = so + 1048576; }
    else if (i < 3670016) { s = (const float4*)wv;  d = (ushort4*)wqkv; so = i - 3407872; dofs = so + 1310720; }
    else                  { s = (const float4*)wo_; d = (ushort4*)wob;  so = i - 3670016; dofs = so; }
    float4 v = s[so];
    ushort4 o;
    o.x = f2bf(v.x); o.y = f2bf(v.y); o.z = f2bf(v.z); o.w = f2bf(v.w);
    d[dofs] = o;
}

// ------------- GEMM: QKV projection, 256x192 tile, 4-phase ------------------
// C = A * B^T, A = xb [4096,2048], B = wqkv [3072,2048]. Grid (16,16) = 256
// blocks (100% fill). Per wave (2x4 grid): 128x48 output, acc[8][3].
// Epilogue: cols <2048 -> Q (scaled), <2560 -> K, >=2560 -> V transposed.
__global__ __launch_bounds__(512, 1)
void gemm256x192(const u16* __restrict__ A, const u16* __restrict__ Bm,
                 int K,
                 u16* __restrict__ qkOut, u16* __restrict__ vtOut)
{
    __shared__ __attribute__((aligned(16))) u16 ldsA[2][2][8192];   // 64 KB
    __shared__ __attribute__((aligned(16))) u16 ldsB[2][12288];     // 48 KB

    const int tid  = threadIdx.x;
    const int lane = tid & 63, quad = lane >> 4, l16 = lane & 15;
    const int wave = tid >> 6;
    const int wr = wave >> 2, wc = wave & 3;

    int bx, by;
    {
        const int nwgx = gridDim.x;
        const int nwg  = nwgx * gridDim.y;
        const int flat = blockIdx.y * nwgx + blockIdx.x;
        const int nflat = (flat & 7) * (nwg >> 3) + (flat >> 3);
        bx = nflat % nwgx; by = nflat / nwgx;
    }
    const int m0 = by * 256, n0 = bx * 192;
    const int NT = K >> 6;                     // 32

    f4 acc[8][3] = {};

#define VMC3() asm volatile("s_waitcnt vmcnt(3)" ::: "memory")
#define VMC0() asm volatile("s_waitcnt vmcnt(0)" ::: "memory")
#define BAR()  __builtin_amdgcn_s_barrier()

    // A half h (128x64 = 2 loads/thread)
#define STGA(bf, h, t) if ((t) < NT) {                                      \
        _Pragma("unroll")                                                   \
        for (int j = 0; j < 2; j++) {                                       \
            int s_ = j * 512 + tid;                                         \
            int r_ = s_ >> 3, cc = s_ & 7;                                  \
            GLD_LDS(A + (size_t)(m0 + (h) * 128 + r_) * K + (t) * 64        \
                      + ((cc ^ (r_ & 7)) << 3),                             \
                    &ldsA[bf][h][(j * 512 + (tid & ~63)) * 8]);             \
        } }

    // B tile (192x64 = 3 loads/thread)
#define STGB(bf, t) if ((t) < NT) {                                         \
        _Pragma("unroll")                                                   \
        for (int j = 0; j < 3; j++) {                                       \
            int s_ = j * 512 + tid;                                         \
            int r_ = s_ >> 3, cc = s_ & 7;                                  \
            GLD_LDS(Bm + (size_t)(n0 + r_) * K + (t) * 64                   \
                       + ((cc ^ (r_ & 7)) << 3),                            \
                    &ldsB[bf][(j * 512 + (tid & ~63)) * 8]);                \
        } }

#define RD_A(bf, qm, ar) {                                                  \
        _Pragma("unroll")                                                   \
        for (int f = 0; f < 4; f++) {                                       \
            int r_ = (qm) * 64 + f * 16 + l16;                              \
            _Pragma("unroll")                                               \
            for (int kc = 0; kc < 2; kc++)                                  \
                ar[f][kc] = *(const s8v*)(&ldsA[bf][wr]                     \
                    [r_ * 64 + (((kc * 4 + quad) ^ (r_ & 7)) << 3)]);       \
        } }

#define RD_B(bf, br) {                                                      \
        _Pragma("unroll")                                                   \
        for (int f = 0; f < 3; f++) {                                       \
            int r_ = wc * 48 + f * 16 + l16;                                \
            _Pragma("unroll")                                               \
            for (int kc = 0; kc < 2; kc++)                                  \
                br[f][kc] = *(const s8v*)(&ldsB[bf]                         \
                    [r_ * 64 + (((kc * 4 + quad) ^ (r_ & 7)) << 3)]);       \
        } }

#define MM(qm, ar, br) {                                                    \
        __builtin_amdgcn_s_setprio(1);                                      \
        _Pragma("unroll")                                                   \
        for (int f = 0; f < 4; f++)                                         \
            _Pragma("unroll")                                               \
            for (int g = 0; g < 3; g++) {                                   \
                acc[(qm)*4+f][g] = __builtin_amdgcn_mfma_f32_16x16x32_bf16( \
                    ar[f][0], br[g][0], acc[(qm)*4+f][g], 0, 0, 0);         \
                acc[(qm)*4+f][g] = __builtin_amdgcn_mfma_f32_16x16x32_bf16( \
                    ar[f][1], br[g][1], acc[(qm)*4+f][g], 0, 0, 0);         \
            }                                                               \
        __builtin_amdgcn_s_setprio(0); }

    // prologue: T0 full (A0 2, A1 2, B 3) -> buf0; T1 B (3) -> buf1.
    // vmcnt(3) drains the 7 T0 loads, leaves T1.B in flight.
    STGA(0,0,0); STGA(0,1,0); STGB(0,0);
    STGB(1,1);
    VMC3(); BAR();

    for (int T = 0; T < NT; T += 2) {
        const bool more = (T + 2 < NT);
        s8v a0[4][2], a1[4][2], b[3][2];
        // P1 (tile T, buf0): stage T+1 A-halves -> buf1
        RD_A(0,0,a0); RD_B(0,b);
        STGA(1,0,T+1); STGA(1,1,T+1);
        BAR(); MM(0,a0,b); BAR();
        // P2: last read of buf0 A; stage T+2 B -> buf0
        RD_A(0,1,a1);
        STGB(0,T+2);
        // drain: T1.B(3) + T+1.A(4) = 7 -> buf1 complete; T+2.B stays
        BAR(); MM(1,a1,b);
        if (more) { VMC3(); } else { VMC0(); }
        BAR();
        // P3 (tile T+1, buf1): stage T+2 A-halves -> buf0
        RD_A(1,0,a0); RD_B(1,b);
        STGA(0,0,T+2); STGA(0,1,T+2);
        BAR(); MM(0,a0,b); BAR();
        // P4: stage T+3 B -> buf1
        RD_A(1,1,a1);
        STGB(1,T+3);
        BAR(); MM(1,a1,b);
        if (more) { VMC3(); } else { VMC0(); }   // buf0 (T+2) complete
        BAR();
    }
#undef STGA
#undef STGB
#undef RD_A
#undef RD_B
#undef MM
#undef VMC3
#undef VMC0
#undef BAR

    // epilogue: fragment base = n0 + wc*48 + ni*16 is a multiple of 16, so a
    // fragment never straddles the 2048 / 2560 boundaries -> uniform branch.
    const float qs = 0.08838834764831845f * 1.4426950408889634f;
    #pragma unroll
    for (int mi = 0; mi < 8; mi++) {
        int gm0 = m0 + wr * 128 + mi * 16 + quad * 4;
        int bb = gm0 >> 11, s = gm0 & 2047;
        #pragma unroll
        for (int ni = 0; ni < 3; ni++) {
            int base = n0 + wc * 48 + ni * 16;
            int gn = base + l16;
            if (base < 2048) {
                #pragma unroll
                for (int r = 0; r < 4; r++)
                    qkOut[(size_t)(gm0 + r) * 2560 + gn] = f2bf(acc[mi][ni][r] * qs);
            } else if (base < 2560) {
                #pragma unroll
                for (int r = 0; r < 4; r++)
                    qkOut[(size_t)(gm0 + r) * 2560 + gn] = f2bf(acc[mi][ni][r]);
            } else {
                int dd = gn - 2560;
                ushort4 pk;
                pk.x = f2bf(acc[mi][ni][0]); pk.y = f2bf(acc[mi][ni][1]);
                pk.z = f2bf(acc[mi][ni][2]); pk.w = f2bf(acc[mi][ni][3]);
                *(ushort4*)(vtOut +
                    ((size_t)(bb * 4 + (dd >> 7)) * 128 + (dd & 127)) * 2048 + s) = pk;
            }
        }
    }
}

// ---------------- GEMM: C = A * B^T  (256x128, 4-phase, fp32 out) -----------
__global__ __launch_bounds__(512, 1)
void gemm256x128(const u16* __restrict__ A, const u16* __restrict__ Bm,
                 int M, int N, int K, float* __restrict__ fOut)
{
    __shared__ __attribute__((aligned(16))) u16 lds[2][3][8192];

    const int tid  = threadIdx.x;
    const int lane = tid & 63, quad = lane >> 4, l16 = lane & 15;
    const int wave = tid >> 6;
    const int wr = wave >> 2, wc = wave & 3;

    int bx, by;
    {
        const int nwgx = gridDim.x;
        const int nwg  = nwgx * gridDim.y;
        const int flat = blockIdx.y * nwgx + blockIdx.x;
        const int nflat = (flat & 7) * (nwg >> 3) + (flat >> 3);
        bx = nflat % nwgx; by = nflat / nwgx;
    }
    const int m0 = by * 256, n0 = bx * 128;
    const int NT = K >> 6;

    f4 acc[8][2] = {};

#define VMC2() asm volatile("s_waitcnt vmcnt(2)" ::: "memory")
#define VMC0() asm volatile("s_waitcnt vmcnt(0)" ::: "memory")
#define BAR()  __builtin_amdgcn_s_barrier()

#define STG(bf, u, t) if ((t) < NT) {                                       \
        const u16* gb = ((u) == 2) ? Bm : A;                                \
        const int rb = ((u) == 2) ? n0 : (m0 + (u) * 128);                  \
        _Pragma("unroll")                                                   \
        for (int j = 0; j < 2; j++) {                                       \
            int s_ = j * 512 + tid;                                         \
            int r_ = s_ >> 3, cc = s_ & 7;                                  \
            GLD_LDS(gb + (size_t)(rb + r_) * K + (t) * 64                   \
                       + ((cc ^ (r_ & 7)) << 3),                            \
                    &lds[bf][u][(j * 512 + (tid & ~63)) * 8]);              \
        } }

#define RD_A(bf, qm, ar) {                                                  \
        _Pragma("unroll")                                                   \
        for (int f = 0; f < 4; f++) {                                       \
            int r_ = (qm) * 64 + f * 16 + l16;                              \
            _Pragma("unroll")                                               \
            for (int kc = 0; kc < 2; kc++)                                  \
                ar[f][kc] = *(const s8v*)(&lds[bf][wr]                      \
                    [r_ * 64 + (((kc * 4 + quad) ^ (r_ & 7)) << 3)]);       \
        } }

#define RD_B(bf, br) {                                                      \
        _Pragma("unroll")                                                   \
        for (int f = 0; f < 2; f++) {                                       \
            int r_ = wc * 32 + f * 16 + l16;                                \
            _Pragma("unroll")                                               \
            for (int kc = 0; kc < 2; kc++)                                  \
                br[f][kc] = *(const s8v*)(&lds[bf][2]                       \
                    [r_ * 64 + (((kc * 4 + quad) ^ (r_ & 7)) << 3)]);       \
        } }

#define MM(qm, ar, br) {                                                    \
        __builtin_amdgcn_s_setprio(1);                                      \
        _Pragma("unroll")                                                   \
        for (int f = 0; f < 4; f++)                                         \
            _Pragma("unroll")                                               \
            for (int g = 0; g < 2; g++) {                                   \
                acc[(qm)*4+f][g] = __builtin_amdgcn_mfma_f32_16x16x32_bf16( \
                    ar[f][0], br[g][0], acc[(qm)*4+f][g], 0, 0, 0);         \
                acc[(qm)*4+f][g] = __builtin_amdgcn_mfma_f32_16x16x32_bf16( \
                    ar[f][1], br[g][1], acc[(qm)*4+f][g], 0, 0, 0);         \
            }                                                               \
        __builtin_amdgcn_s_setprio(0); }

    STG(0,0,0); STG(0,1,0); STG(0,2,0);
    STG(1,2,1);
    VMC2(); BAR();

    for (int T = 0; T < NT; T += 2) {
        const bool more = (T + 2 < NT);
        s8v a0[4][2], a1[4][2], b[2][2];
        RD_A(0,0,a0); RD_B(0,b);
        STG(1,0,T+1); STG(1,1,T+1);
        BAR(); MM(0,a0,b); BAR();
        RD_A(0,1,a1);
        STG(0,2,T+2);
        BAR(); MM(1,a1,b);
        if (more) { VMC2(); } else { VMC0(); }
        BAR();
        RD_A(1,0,a0); RD_B(1,b);
        STG(0,0,T+2); STG(0,1,T+2);
        BAR(); MM(0,a0,b); BAR();
        RD_A(1,1,a1);
        STG(1,2,T+3);
        BAR(); MM(1,a1,b);
        if (more) { VMC2(); } else { VMC0(); }
        BAR();
    }
#undef STG
#undef RD_A
#undef RD_B
#undef MM
#undef VMC2
#undef VMC0
#undef BAR

    #pragma unroll
    for (int mi = 0; mi < 8; mi++) {
        int gm0 = m0 + wr * 128 + mi * 16 + quad * 4;
        #pragma unroll
        for (int ni = 0; ni < 2; ni++) {
            int gn = n0 + wc * 32 + ni * 16 + l16;
            #pragma unroll
            for (int r = 0; r < 4; r++)
                fOut[(size_t)(gm0 + r) * N + gn] = acc[mi][ni][r];
        }
    }
}

// ------------------------------- attention ----------------------------------
// grid = (B*NKV, S/64), 512 threads = 8 waves, wave = (head hh, m-half mh).
// Swapped QK^T, P staged via 8x ds_write_b64 + b128 reads; no max-tracking.
__global__ __launch_bounds__(512, 2)
void attn_kernel(const u16* __restrict__ qk, const u16* __restrict__ vt,
                 u16* __restrict__ ao)
{
    __shared__ __attribute__((aligned(16))) u16 Kb[2][64 * 128];  // 32 KB
    __shared__ __attribute__((aligned(16))) u16 Vb[2][128 * 64];  // 32 KB
    __shared__ __attribute__((aligned(16))) u16 Ps[8][32 * 72];   // 36 KB

    const int tid  = threadIdx.x;
    const int wave = tid >> 6, lane = tid & 63;
    const int quad = lane >> 4, l16 = lane & 15;
    const int bh = blockIdx.x;                 // 0..7 = b*4+h  (XCD = bh)
    const int b = bh >> 2, h = bh & 3;
    const int hh = wave >> 1, mh = wave & 1;   // head-in-group, m-half
    const int hq = h * 4 + hh;                 // global q-head
    const int qs0 = blockIdx.y * 64;

    s8v aq[2][4];
    #pragma unroll
    for (int mt = 0; mt < 2; mt++) {
        const u16* qrow = qk + (size_t)(b * 2048 + qs0 + (mh * 2 + mt) * 16 + l16) * 2560
                             + hq * 128 + quad * 8;
        #pragma unroll
        for (int c4 = 0; c4 < 4; c4++) aq[mt][c4] = *(const s8v*)(qrow + c4 * 32);
    }

    s8v ones;
    #pragma unroll
    for (int j = 0; j < 8; j++) ones[j] = (short)0x3F80;   // bf16 1.0

    f4 o[2][9] = {};          // 8 d-channels + [8] = row-sum l_i

    const u16* kbase = qk + (size_t)(b * 2048) * 2560 + 2048 + h * 128;
    const u16* vbase = vt + (size_t)bh * 128 * 2048;
    u16* Pw = &Ps[wave][0];

    int bkb[4], bvb[2];
    #pragma unroll
    for (int c4 = 0; c4 < 4; c4++)
        bkb[c4] = l16 * 128 + (((c4 * 4 + quad) ^ (l16 & 7)) * 8);
    #pragma unroll
    for (int kc = 0; kc < 2; kc++)
        bvb[kc] = l16 * 64 + (((kc * 4 + quad) ^ (l16 & 7)) * 8);
    const int apb = l16 * 72 + quad * 8;        // + mt*1152 + kc*32
    const int psw = l16 * 72 + quad * 4;        // + mt*1152 + cg*16 (b64 write)

#define STAGE(CUR, S) {                                                       \
        _Pragma("unroll")                                                     \
        for (int i = 0; i < 2; i++) {                                         \
            const int c = wave + i * 8;                                       \
            int kr = c * 4 + (lane >> 4);                                     \
            int ksw = (lane & 15) ^ (kr & 7);                                 \
            GLD_LDS(kbase + (size_t)((S) + kr) * 2560 + ksw * 8,              \
                    &Kb[CUR][c * 512]);                                       \
            int vd = c * 8 + (lane >> 3);                                     \
            int vsw = (lane & 7) ^ (vd & 7);                                  \
            GLD_LDS(vbase + (size_t)vd * 2048 + (S) + vsw * 8,                \
                    &Vb[CUR][c * 512]);                                       \
        } }

#define STEP(CUR, S) {                                                        \
        __syncthreads();  /* completes buf CUR staging (issued last iter) */  \
        if ((S) + 64 < 2048) STAGE((CUR) ^ 1, (S) + 64);                      \
        s8v bk[4][4];                                                         \
        _Pragma("unroll")                                                     \
        for (int c4 = 0; c4 < 4; c4++)                                        \
            _Pragma("unroll")                                                 \
            for (int cg = 0; cg < 4; cg++)                                    \
                bk[c4][cg] = *(const s8v*)(&Kb[CUR][bkb[c4] + cg * 2048]);    \
        _Pragma("unroll")                                                     \
        for (int mt = 0; mt < 2; mt++) {                                      \
            f4 sc[4] = {};                                                    \
            _Pragma("unroll")                                                 \
            for (int c4 = 0; c4 < 4; c4++)                                    \
                _Pragma("unroll")                                             \
                for (int cg = 0; cg < 4; cg++)                                \
                    sc[cg] = __builtin_amdgcn_mfma_f32_16x16x32_bf16(         \
                        bk[c4][cg], aq[mt][c4], sc[cg], 0, 0, 0);             \
            _Pragma("unroll")                                                 \
            for (int cg = 0; cg < 4; cg++) {                                  \
                ushort4 pk;                                                   \
                pk.x = (u16)(__float_as_uint(fexp2(sc[cg][0])) >> 16);        \
                pk.y = (u16)(__float_as_uint(fexp2(sc[cg][1])) >> 16);        \
                pk.z = (u16)(__float_as_uint(fexp2(sc[cg][2])) >> 16);        \
                pk.w = (u16)(__float_as_uint(fexp2(sc[cg][3])) >> 16);        \
                *(ushort4*)(Pw + psw + mt * 1152 + cg * 16) = pk;             \
            }                                                                 \
        }                                                                     \
        s8v ap[2][2];                                                         \
        _Pragma("unroll")                                                     \
        for (int mt = 0; mt < 2; mt++)                                        \
            _Pragma("unroll")                                                 \
            for (int kc = 0; kc < 2; kc++)                                    \
                ap[mt][kc] = *(const s8v*)(Pw + apb + mt * 1152 + kc * 32);   \
        _Pragma("unroll")                                                     \
        for (int ch = 0; ch < 8; ch++) {                                      \
            s8v bv0 = *(const s8v*)(&Vb[CUR][bvb[0] + ch * 1024]);            \
            s8v bv1 = *(const s8v*)(&Vb[CUR][bvb[1] + ch * 1024]);            \
            _Pragma("unroll")                                                 \
            for (int mt = 0; mt < 2; mt++) {                                  \
                o[mt][ch] = __builtin_amdgcn_mfma_f32_16x16x32_bf16(          \
                    ap[mt][0], bv0, o[mt][ch], 0, 0, 0);                      \
                o[mt][ch] = __builtin_amdgcn_mfma_f32_16x16x32_bf16(          \
                    ap[mt][1], bv1, o[mt][ch], 0, 0, 0);                      \
            }                                                                 \
        }                                                                     \
        _Pragma("unroll")                                                     \
        for (int mt = 0; mt < 2; mt++) {                                      \
            o[mt][8] = __builtin_amdgcn_mfma_f32_16x16x32_bf16(               \
                ap[mt][0], ones, o[mt][8], 0, 0, 0);                          \
            o[mt][8] = __builtin_amdgcn_mfma_f32_16x16x32_bf16(               \
                ap[mt][1], ones, o[mt][8], 0, 0, 0);                          \
        } }

    STAGE(0, 0);
    for (int s0 = 0; s0 < 2048; s0 += 128) {
        STEP(0, s0);
        STEP(1, s0 + 64);
    }
#undef STEP
#undef STAGE

    #pragma unroll
    for (int mt = 0; mt < 2; mt++)
        #pragma unroll
        for (int r = 0; r < 4; r++) {
            float inv = 1.f / o[mt][8][r];
            int gm = b * 2048 + qs0 + (mh * 2 + mt) * 16 + quad * 4 + r;
            #pragma unroll
            for (int ch = 0; ch < 8; ch++)
                ao[(size_t)gm * 2048 + hq * 128 + ch * 16 + l16] =
                    f2bf(o[mt][ch][r] * inv);
        }
}

// ------------------------------- launcher -----------------------------------
extern "C" void kernel_launch(void* const* d_in, const int* in_sizes, int n_in,
                              void* d_out, int out_size, void* d_ws, size_t ws_size,
                              hipStream_t stream)
{
    const float* x  = (const float*)d_in[0];
    const float* Wq = (const float*)d_in[3];
    const float* Wk = (const float*)d_in[4];
    const float* Wv = (const float*)d_in[5];
    const float* Wo = (const float*)d_in[6];

    char* ws = (char*)d_ws;
    u16* xb   = (u16*)(ws);                 // 4096x2048
    u16* wqkv = (u16*)(ws + 16777216);      // 3072x2048
    u16* wo   = (u16*)(ws + 29360128);      // 2048x2048
    u16* qkb  = (u16*)(ws + 37748736);      // 4096x2560
    u16* vtb  = (u16*)(ws + 58720256);      // 2x4x128x2048
    u16* ao   = (u16*)(ws + 62914560);      // 4096x2048
    if (ws_size < 79691776u) return;

    cvt_all<<<18432, 256, 0, stream>>>(x, Wq, Wk, Wv, Wo, xb, wqkv, wo);

    gemm256x192<<<dim3(16, 16), 512, 0, stream>>>(xb, wqkv, 2048, qkb, vtb);
    attn_kernel<<<dim3(8, 32), 512, 0, stream>>>(qkb, vtb, ao);
    gemm256x128<<<dim3(16, 16), 512, 0, stream>>>(ao, wo, 4096, 2048, 2048,
                                                  (float*)d_out);
}